// Round 3
// baseline (249.844 us; speedup 1.0000x reference)
//
#include <hip/hip_runtime.h>

#define COLS 117
#define NOUT1 20
#define ROWS 64                 // rows per tile
#define TILEF (ROWS * COLS)     // 7488 floats / tile (29,952 B)
#define NV (TILEF / 4)          // 1872 float4 / tile
#define REM (NV - 7 * 256)      // 80 leftover float4 after 7 full sweeps
#define PSTR 21                 // padded partial stride (odd -> conflict-free)
#define PFROW (ROWS * PSTR)     // 1344
#define PFSZ (4 * PFROW)        // 5376 floats (partials region inside scr)
#define GRID 512                // 2 blocks/CU * 256 CUs (LDS-capped at 2/CU)

// requant: y = x*m (fp32 round), y += off (fp32 round), trunc toward zero to
// int64, arithmetic >> s, clamp [0,255]. Matches jnp reference exactly.
__device__ __forceinline__ float requant(float x, float m, float off, int s) {
  float y = __fmul_rn(x, m);
  y = __fadd_rn(y, off);
  long long yi = (long long)y;   // trunc toward zero, like astype(int64)
  yi >>= s;                      // arithmetic shift
  float r = (float)yi;
  return fminf(fmaxf(r, 0.0f), 255.0f);
}

// Transpose W1 [20,117] -> W1T [117,20]: weights for a given k contiguous.
__global__ void transpose_w1(const float* __restrict__ W1, float* __restrict__ w1t) {
  for (int idx = threadIdx.x; idx < NOUT1 * COLS; idx += blockDim.x) {
    int o = idx / COLS, k = idx % COLS;
    w1t[k * NOUT1 + o] = W1[idx];
  }
}

// Persistent double-buffered pipeline. Per tile iteration:
//   issue next-tile global float4 loads into VGPRs   (overlaps everything)
//   k-loop on buf[cur] (4 waves split columns; scalar weights via W1T)
//   barrier#1  -> ds_write staged regs into buf[cur^1]; write layer-1 partials
//   barrier#2  -> cross-wave reduce + requant + layer-2 partials
//   barrier#3  -> lanes<64 finish layer 2, write float2 out
// buf[cur^1] hazard: last readers of it passed barrier#1 of the PREVIOUS
// iteration. scr(t) final-readers pass next iteration's barrier#1 before any
// write touches it, so no 4th barrier is needed.
template <bool TW>
__global__ __launch_bounds__(256, 2) void fann_persistent(
    const float* __restrict__ X, const float* __restrict__ W1,
    const float* __restrict__ b1, const float* __restrict__ W2,
    const float* __restrict__ b2, float* __restrict__ out, int ntiles) {
  __shared__ __align__(16) float buf[2][TILEF];   // 59,904 B -> 2 blocks/CU
  const int t256 = threadIdx.x;
  const int w = __builtin_amdgcn_readfirstlane(t256 >> 6);  // wave id (SGPR)
  const int l = t256 & 63;                                  // row within tile
  const int k0 = w * 29;
  const int kn = (w == 3) ? 30 : 29;       // wave-uniform trip count
  const int G = gridDim.x;
  const float4* __restrict__ Xv = reinterpret_cast<const float4*>(X);

  int cur = 0;
  int t = blockIdx.x;
  if (t < ntiles) {  // prologue: stage tile t into buf[0]
    const float4* src = Xv + (size_t)t * NV;
    float4 rr[8];
    #pragma unroll
    for (int i = 0; i < 7; ++i) rr[i] = src[t256 + i * 256];
    if (t256 < REM) rr[7] = src[t256 + 7 * 256];
    float4* d = (float4*)buf[0];
    #pragma unroll
    for (int i = 0; i < 7; ++i) d[t256 + i * 256] = rr[i];
    if (t256 < REM) d[t256 + 7 * 256] = rr[7];
  }
  __syncthreads();

  for (; t < ntiles; t += G) {
    const int tn = t + G;
    const bool pf = (tn < ntiles);
    float4 rr[8];
    if (pf) {  // issue next-tile loads NOW; consumed after barrier#1
      const float4* src = Xv + (size_t)tn * NV;
      #pragma unroll
      for (int i = 0; i < 7; ++i) rr[i] = src[t256 + i * 256];
      if (t256 < REM) rr[7] = src[t256 + 7 * 256];
    }

    // ---- layer 1 k-loop on current buffer ----
    float acc[NOUT1];
    #pragma unroll
    for (int o = 0; o < NOUT1; ++o) acc[o] = 0.0f;
    const float* xr = buf[cur] + l * COLS + k0;  // stride 117 (odd) -> free
    if (TW) {
      const float4* __restrict__ w4 =
          reinterpret_cast<const float4*>(W1) + (size_t)k0 * (NOUT1 / 4);
      for (int kk = 0; kk < kn; ++kk) {
        float x = xr[kk];
        #pragma unroll
        for (int j = 0; j < 5; ++j) {
          float4 wv = w4[kk * 5 + j];   // uniform address -> scalar load
          acc[4 * j + 0] = fmaf(x, wv.x, acc[4 * j + 0]);
          acc[4 * j + 1] = fmaf(x, wv.y, acc[4 * j + 1]);
          acc[4 * j + 2] = fmaf(x, wv.z, acc[4 * j + 2]);
          acc[4 * j + 3] = fmaf(x, wv.w, acc[4 * j + 3]);
        }
      }
    } else {
      for (int kk = 0; kk < kn; ++kk) {
        float x = xr[kk];
        #pragma unroll
        for (int o = 0; o < NOUT1; ++o)
          acc[o] = fmaf(x, W1[o * COLS + k0 + kk], acc[o]);
      }
    }
    __syncthreads();  // #1: all x reads of buf[cur] done

    if (pf) {  // staged regs -> other buffer (free since prev iter's #1)
      float4* d = (float4*)buf[cur ^ 1];
      #pragma unroll
      for (int i = 0; i < 7; ++i) d[t256 + i * 256] = rr[i];
      if (t256 < REM) d[t256 + 7 * 256] = rr[7];
    }
    float* scr = buf[cur];  // scribble over consumed x data
    {
      float* pw = scr + w * PFROW + l * PSTR;
      #pragma unroll
      for (int o = 0; o < NOUT1; ++o) pw[o] = acc[o];
    }
    __syncthreads();  // #2

    // ---- cross-wave reduce, requant, layer 2 partials ----
    float* sp0 = scr + PFSZ;       // [4][65]
    float* sp1 = sp0 + 4 * 65;     // ends at 6416 < 7488
    {
      float s0 = 0.0f, s1 = 0.0f;
      #pragma unroll
      for (int j = 0; j < 5; ++j) {
        const int o = w * 5 + j;
        float h = scr[0 * PFROW + l * PSTR + o] + scr[1 * PFROW + l * PSTR + o] +
                  scr[2 * PFROW + l * PSTR + o] + scr[3 * PFROW + l * PSTR + o];
        h += b1[o];
        float hq = requant(h, 1565.0f, 16384.0f, 15);
        s0 = fmaf(hq, W2[o], s0);
        s1 = fmaf(hq, W2[NOUT1 + o], s1);
      }
      sp0[w * 65 + l] = s0;
      sp1[w * 65 + l] = s1;
    }
    __syncthreads();  // #3

    if (t256 < ROWS) {
      float s0 = sp0[t256] + sp0[65 + t256] + sp0[130 + t256] + sp0[195 + t256] + b2[0];
      float s1 = sp1[t256] + sp1[65 + t256] + sp1[130 + t256] + sp1[195 + t256] + b2[1];
      float2 r;
      r.x = requant(s0, 1342.0f, 16384.0f, 15);
      r.y = requant(s1, 1342.0f, 16384.0f, 15);
      reinterpret_cast<float2*>(out)[(size_t)t * ROWS + t256] = r;
    }
    cur ^= 1;
  }
}

// Tail for row counts not divisible by ROWS (not hit for B=1048576).
__global__ void fann_tail(const float* __restrict__ X, const float* __restrict__ W1,
                          const float* __restrict__ b1, const float* __restrict__ W2,
                          const float* __restrict__ b2, float* __restrict__ out,
                          int start, int B) {
  int row = start + blockIdx.x * blockDim.x + threadIdx.x;
  if (row >= B) return;
  float acc[NOUT1];
  #pragma unroll
  for (int o = 0; o < NOUT1; ++o) acc[o] = b1[o];
  const float* xr = X + (size_t)row * COLS;
  for (int k = 0; k < COLS; ++k) {
    float x = xr[k];
    #pragma unroll
    for (int o = 0; o < NOUT1; ++o) acc[o] = fmaf(x, W1[o * COLS + k], acc[o]);
  }
  float s0 = b2[0], s1 = b2[1];
  #pragma unroll
  for (int o = 0; o < NOUT1; ++o) {
    float hq = requant(acc[o], 1565.0f, 16384.0f, 15);
    s0 = fmaf(hq, W2[o], s0);
    s1 = fmaf(hq, W2[NOUT1 + o], s1);
  }
  out[(size_t)row * 2 + 0] = requant(s0, 1342.0f, 16384.0f, 15);
  out[(size_t)row * 2 + 1] = requant(s1, 1342.0f, 16384.0f, 15);
}

extern "C" void kernel_launch(void* const* d_in, const int* in_sizes, int n_in,
                              void* d_out, int out_size, void* d_ws, size_t ws_size,
                              hipStream_t stream) {
  const float* X  = (const float*)d_in[0];
  const float* W1 = (const float*)d_in[1];
  const float* b1 = (const float*)d_in[2];
  const float* W2 = (const float*)d_in[3];
  const float* b2 = (const float*)d_in[4];
  float* out = (float*)d_out;
  const int B = in_sizes[0] / COLS;
  const int ntiles = B / ROWS;
  const int tail = B - ntiles * ROWS;
  const int grid = (ntiles < GRID) ? (ntiles > 0 ? ntiles : 1) : GRID;

  const bool useT = ws_size >= (size_t)(COLS * NOUT1 * sizeof(float));
  if (useT) {
    float* w1t = (float*)d_ws;
    transpose_w1<<<1, 256, 0, stream>>>(W1, w1t);
    if (ntiles > 0)
      fann_persistent<true><<<grid, 256, 0, stream>>>(X, w1t, b1, W2, b2, out, ntiles);
  } else {
    if (ntiles > 0)
      fann_persistent<false><<<grid, 256, 0, stream>>>(X, W1, b1, W2, b2, out, ntiles);
  }
  if (tail > 0)
    fann_tail<<<(tail + 63) / 64, 64, 0, stream>>>(X, W1, b1, W2, b2, out,
                                                   ntiles * ROWS, B);
}

// Round 4
// 117.545 us; speedup vs baseline: 2.1255x; 2.1255x over previous
//
#include <hip/hip_runtime.h>

#define COLS 117
#define NOUT1 20
#define ROWS 64            // rows per block
#define NV (ROWS * COLS / 4)   // 1872 float4 per tile
#define REM (NV - 7 * 256)     // 80 leftover float4 after 7 full sweeps
#define PSTR 21            // padded partial stride (odd -> bank-conflict-free)
#define PFROW (ROWS * PSTR)

// requant: y = x*m (fp32 round), y += off (fp32 round), trunc toward zero to
// int64, arithmetic >> s, clamp [0,255]. Matches jnp reference exactly.
__device__ __forceinline__ float requant(float x, float m, float off, int s) {
  float y = __fmul_rn(x, m);
  y = __fadd_rn(y, off);
  long long yi = (long long)y;   // trunc toward zero, like astype(int64)
  yi >>= s;                      // arithmetic shift
  float r = (float)yi;
  return fminf(fmaxf(r, 0.0f), 255.0f);
}

// Transpose W1 [20,117] -> W1T [117,20]: weights for a given k contiguous.
__global__ void transpose_w1(const float* __restrict__ W1, float* __restrict__ w1t) {
  for (int idx = threadIdx.x; idx < NOUT1 * COLS; idx += blockDim.x) {
    int o = idx / COLS, k = idx % COLS;
    w1t[k * NOUT1 + o] = W1[idx];
  }
}

// One-shot blocks (R2 structure — 5 blocks/CU gives the cross-block overlap
// that hides staging latency; persistent+prefetch regressed 2.3x in R3 due to
// __syncthreads vmcnt(0) drains + occupancy loss).
// 256 threads = 4 waves; wave w handles column-quarter w of all 64 rows;
// lane = row. Weight addresses wave-uniform -> scalar s_loads.
// 3 barriers: post-stage, post-kloop (scr reuse hazard), partials-visible.
// Wave 0 alone finalizes (removes R2's 4th barrier + sp round-trip).
template <bool TW>
__global__ __launch_bounds__(256, 5) void fann_kernel(
    const float* __restrict__ X, const float* __restrict__ W1,
    const float* __restrict__ b1, const float* __restrict__ W2,
    const float* __restrict__ b2, float* __restrict__ out) {
  __shared__ __align__(16) float xs[ROWS * COLS];  // 29,952 B -> 5 blocks/CU
  float4* xs4 = (float4*)xs;
  const int t = threadIdx.x;
  {
    const float4* __restrict__ src =
        reinterpret_cast<const float4*>(X + (size_t)blockIdx.x * (ROWS * COLS));
    #pragma unroll
    for (int i = 0; i < 7; ++i) xs4[t + i * 256] = src[t + i * 256];
    if (t < REM) xs4[t + 7 * 256] = src[t + 7 * 256];
  }
  __syncthreads();  // #0: tile staged

  const int w = __builtin_amdgcn_readfirstlane(t >> 6);  // wave id in SGPR
  const int l = t & 63;                                  // row within tile
  const int k0 = w * 29;
  const int kn = (w == 3) ? 30 : 29;   // wave-uniform trip count

  float acc[NOUT1];
  #pragma unroll
  for (int o = 0; o < NOUT1; ++o) acc[o] = 0.0f;
  const float* xr = xs + l * COLS + k0;  // stride 117 (odd) -> 2-way = free

  if (TW) {
    const float4* __restrict__ w4 =
        reinterpret_cast<const float4*>(W1) + (size_t)k0 * (NOUT1 / 4);
    for (int kk = 0; kk < kn; ++kk) {
      float x = xr[kk];
      #pragma unroll
      for (int j = 0; j < 5; ++j) {
        float4 wv = w4[kk * 5 + j];   // uniform address -> s_load
        acc[4 * j + 0] = fmaf(x, wv.x, acc[4 * j + 0]);
        acc[4 * j + 1] = fmaf(x, wv.y, acc[4 * j + 1]);
        acc[4 * j + 2] = fmaf(x, wv.z, acc[4 * j + 2]);
        acc[4 * j + 3] = fmaf(x, wv.w, acc[4 * j + 3]);
      }
    }
  } else {
    for (int kk = 0; kk < kn; ++kk) {
      float x = xr[kk];
      #pragma unroll
      for (int o = 0; o < NOUT1; ++o)
        acc[o] = fmaf(x, W1[o * COLS + k0 + kk], acc[o]);
    }
  }
  __syncthreads();  // #1: all x reads of xs done -> safe to overwrite

  {
    float* pw = xs + w * PFROW + l * PSTR;
    #pragma unroll
    for (int o = 0; o < NOUT1; ++o) pw[o] = acc[o];
  }
  __syncthreads();  // #2: partials visible

  // Wave 0 finalizes all 64 rows; waves 1-3 exit. Summation order replicated
  // exactly from the absmax=0 R2 version: per-o quarter sum q0+q1+q2+q3, then
  // +b1; layer-2 as four 5-output group sums combined left-assoc, then +b2.
  if (t < ROWS) {
    float g0[2] = {0.f, 0.f}, g1[2] = {0.f, 0.f};
    float g2[2] = {0.f, 0.f}, g3[2] = {0.f, 0.f};
    #pragma unroll
    for (int o = 0; o < NOUT1; ++o) {
      float h = xs[0 * PFROW + t * PSTR + o] + xs[1 * PFROW + t * PSTR + o] +
                xs[2 * PFROW + t * PSTR + o] + xs[3 * PFROW + t * PSTR + o];
      h += b1[o];
      float hq = requant(h, 1565.0f, 16384.0f, 15);
      float* g = (o < 5) ? g0 : (o < 10) ? g1 : (o < 15) ? g2 : g3;
      g[0] = fmaf(hq, W2[o], g[0]);
      g[1] = fmaf(hq, W2[NOUT1 + o], g[1]);
    }
    float s0 = g0[0] + g1[0] + g2[0] + g3[0] + b2[0];
    float s1 = g0[1] + g1[1] + g2[1] + g3[1] + b2[1];
    float2 r;
    r.x = requant(s0, 1342.0f, 16384.0f, 15);
    r.y = requant(s1, 1342.0f, 16384.0f, 15);
    reinterpret_cast<float2*>(out)[(size_t)blockIdx.x * ROWS + t] = r;
  }
}

// Tail for row counts not divisible by ROWS (not hit for B=1048576).
__global__ void fann_tail(const float* __restrict__ X, const float* __restrict__ W1,
                          const float* __restrict__ b1, const float* __restrict__ W2,
                          const float* __restrict__ b2, float* __restrict__ out,
                          int start, int B) {
  int row = start + blockIdx.x * blockDim.x + threadIdx.x;
  if (row >= B) return;
  float acc[NOUT1];
  #pragma unroll
  for (int o = 0; o < NOUT1; ++o) acc[o] = b1[o];
  const float* xr = X + (size_t)row * COLS;
  for (int k = 0; k < COLS; ++k) {
    float x = xr[k];
    #pragma unroll
    for (int o = 0; o < NOUT1; ++o) acc[o] = fmaf(x, W1[o * COLS + k], acc[o]);
  }
  float s0 = b2[0], s1 = b2[1];
  #pragma unroll
  for (int o = 0; o < NOUT1; ++o) {
    float hq = requant(acc[o], 1565.0f, 16384.0f, 15);
    s0 = fmaf(hq, W2[o], s0);
    s1 = fmaf(hq, W2[NOUT1 + o], s1);
  }
  out[(size_t)row * 2 + 0] = requant(s0, 1342.0f, 16384.0f, 15);
  out[(size_t)row * 2 + 1] = requant(s1, 1342.0f, 16384.0f, 15);
}

extern "C" void kernel_launch(void* const* d_in, const int* in_sizes, int n_in,
                              void* d_out, int out_size, void* d_ws, size_t ws_size,
                              hipStream_t stream) {
  const float* X  = (const float*)d_in[0];
  const float* W1 = (const float*)d_in[1];
  const float* b1 = (const float*)d_in[2];
  const float* W2 = (const float*)d_in[3];
  const float* b2 = (const float*)d_in[4];
  float* out = (float*)d_out;
  const int B = in_sizes[0] / COLS;
  const int nblk = B / ROWS;
  const int tail = B - nblk * ROWS;

  const bool useT = ws_size >= (size_t)(COLS * NOUT1 * sizeof(float));
  if (useT) {
    float* w1t = (float*)d_ws;
    transpose_w1<<<1, 256, 0, stream>>>(W1, w1t);
    if (nblk > 0)
      fann_kernel<true><<<nblk, 256, 0, stream>>>(X, w1t, b1, W2, b2, out);
  } else {
    if (nblk > 0)
      fann_kernel<false><<<nblk, 256, 0, stream>>>(X, W1, b1, W2, b2, out);
  }
  if (tail > 0)
    fann_tail<<<(tail + 63) / 64, 64, 0, stream>>>(X, W1, b1, W2, b2, out,
                                                   nblk * ROWS, B);
}